// Round 6
// baseline (35.173 us; speedup 1.0000x reference)
//
#include <hip/hip_runtime.h>
#include <hip/hip_bf16.h>
#include <math.h>

// Problem constants
#define Bn    8
#define Sn    8
#define COUTc 128
#define PWc   73728
#define Pc    73856
#define WOc   30
#define NPIX  900      // 30*30 per (b,s)
#define GPIX  7200     // B*NPIX per s
#define NSTEP 9        // one r=(ky,kx) per K-step, 64 ci each
#define TILE  128      // pixels per block
#define NT2   57       // ceil(7200/128)

typedef __bf16 bf16;
typedef bf16  bf16x8 __attribute__((ext_vector_type(8)));
typedef float f32x16 __attribute__((ext_vector_type(16)));

__device__ __forceinline__ float softplus_f(float x) {
    return fmaxf(x, 0.f) + log1pf(expf(-fabsf(x)));
}

__device__ __forceinline__ unsigned int pack2(float a, float b) {
    unsigned short ua = __builtin_bit_cast(unsigned short, (bf16)a);
    unsigned short ub = __builtin_bit_cast(unsigned short, (bf16)b);
    return ((unsigned int)ub << 16) | (unsigned int)ua;
}

// global->LDS direct copy, 16B per lane. LDS dest = wave-uniform base
// (+ implicit lane*16); global src is per-lane.
__device__ __forceinline__ void gl16(const void* g, void* l) {
    typedef __attribute__((address_space(1))) void gvoid;
    typedef __attribute__((address_space(3))) void lvoid;
    __builtin_amdgcn_global_load_lds((gvoid*)g, (lvoid*)l, 16, 0, 0);
}

// ---------------------------------------------------------------------------
// Kernel 1 (fused): blocks 0..511 = xcast (x fp32 NCHW -> xt bf16 NHWC),
// blocks 512..543 = W sampling (1 thread per (co,ci), 9 taps each) into the
// swizzled per-(s,r) LDS images, block 544 = bias sampling.
// Prep blocks write KL partials to slots[33*2] unconditionally.
// wimg page (s,r): element (co<<6) + (((ci>>3)^(co&7))<<3) + (ci&7).
// ---------------------------------------------------------------------------
__global__ __launch_bounds__(256) void prep_all(
        const float* __restrict__ xg, const float* __restrict__ e,
        const float* __restrict__ mu_w, const float* __restrict__ rho_w,
        const float* __restrict__ mu_b, const float* __restrict__ rho_b,
        bf16* __restrict__ xt, bf16* __restrict__ wimg,
        float* __restrict__ bq, float* __restrict__ slots) {
    const int bid = blockIdx.x;
    const int t   = threadIdx.x;

    if (bid < 512) {  // ---- xcast
        const int img  = bid >> 3;
        const int part = bid & 7;
        const int p    = part * 128 + (t >> 1);
        const int half = t & 1;
        const float* src = xg + ((size_t)img << 16) + (size_t)(half * 32) * 1024 + p;
        bf16*        dst = xt + ((size_t)img << 16) + (size_t)p * 64 + half * 32;
        #pragma unroll
        for (int o = 0; o < 4; ++o) {
            uint4 pk;
            pk.x = pack2(src[(o * 8 + 0) * 1024], src[(o * 8 + 1) * 1024]);
            pk.y = pack2(src[(o * 8 + 2) * 1024], src[(o * 8 + 3) * 1024]);
            pk.z = pack2(src[(o * 8 + 4) * 1024], src[(o * 8 + 5) * 1024]);
            pk.w = pack2(src[(o * 8 + 6) * 1024], src[(o * 8 + 7) * 1024]);
            *reinterpret_cast<uint4*>(dst + o * 8) = pk;
        }
        return;
    }

    float ls = 0.f, sq = 0.f;
    if (bid < 544) {  // ---- W prep: thread = one (co,ci) pair, 9 taps
        const int gidx = (bid - 512) * 256 + t;   // 0..8191
        const int co   = gidx >> 6;
        const int ci   = gidx & 63;
        const int p0   = co * 576 + ci * 9;
        float mu[9], sg[9];
        #pragma unroll
        for (int r = 0; r < 9; ++r) {
            mu[r] = mu_w[p0 + r];
            sg[r] = softplus_f(rho_w[p0 + r]);
            ls   += logf(sg[r]);
        }
        const int dstp = (co << 6) + (((ci >> 3) ^ (co & 7)) << 3) + (ci & 7);
        #pragma unroll
        for (int s = 0; s < Sn; ++s) {
            const float* es = e + s * Pc + p0;
            #pragma unroll
            for (int r = 0; r < 9; ++r) {
                float wv = fmaf(sg[r], es[r], mu[r]);
                wimg[((s * NSTEP + r) << 13) + dstp] = (bf16)wv;
                sq += wv * wv;
            }
        }
    } else {          // ---- bias prep (bid == 544)
        if (t < COUTc) {
            float sig = softplus_f(rho_b[t]);
            ls = logf(sig);
            float mu = mu_b[t];
            #pragma unroll
            for (int s = 0; s < Sn; ++s) {
                float bv = fmaf(sig, e[s * Pc + PWc + t], mu);
                bq[s * COUTc + t] = bv;
                sq += bv * bv;
            }
        }
    }

    #pragma unroll
    for (int off = 32; off > 0; off >>= 1) {
        ls += __shfl_down(ls, off);
        sq += __shfl_down(sq, off);
    }
    __shared__ float sls[4], ssq[4];
    const int lane = t & 63, wd = t >> 6;
    if (lane == 0) { sls[wd] = ls; ssq[wd] = sq; }
    __syncthreads();
    if (t == 0) {
        slots[2 * (bid - 512)]     = sls[0] + sls[1] + sls[2] + sls[3];
        slots[2 * (bid - 512) + 1] = ssq[0] + ssq[1] + ssq[2] + ssq[3];
    }
}

// ---------------------------------------------------------------------------
// Kernel 2: implicit-GEMM conv. Block = 128 threads (2 waves), tile
// 128co x 128pix; wave tile 64co x 128pix -> 6 ds_read_b128 per 8 MFMA.
// mfma_f32_32x32x16_bf16, BK=64 (one r per step). Double-buffered LDS
// (64 KB -> 2 blocks/CU; epilogue of one block overlaps the other's loop).
// All staging via global_load_lds with the XOR swizzle pre-baked in the
// global sources; counted vmcnt(16) + raw s_barrier; last iters peeled.
// s = bid&7 -> XCD-affine; KL finalize folded into block 0.
// ---------------------------------------------------------------------------
__global__ __launch_bounds__(128) void conv_mfma(
        const bf16* __restrict__ xt, const bf16* __restrict__ wimg,
        const float* __restrict__ bq, const float* __restrict__ slots,
        float* __restrict__ out, float* __restrict__ klout) {
    const int bid  = blockIdx.x;
    const int s    = bid & 7;
    const int tile = bid >> 3;
    const int t    = threadIdx.x;
    const int lane = t & 63;
    const int w    = t >> 6;          // wave id (0/1) = co half

    __shared__ bf16 Wbuf[2][8192];    // 2 x 16 KB  [co 0..127][ci-oct swz]
    __shared__ bf16 Xbuf[2][8192];    // 2 x 16 KB  [pix 0..127][ci-oct swz]

    // W staging source: wimg page is the exact LDS byte image; wave w takes
    // the co rows [64w, 64w+64) = bytes [8192w, 8192w+8192).
    const char* wsrcL = (const char*)wimg + ((size_t)(s * NSTEP) << 14)
                      + (w << 13) + (lane << 4);

    // X staging sources: wave w stages pix rows [64w, 64w+64), 8 chunks of
    // 8 rows; lane fills ci-octet slot (lane&7), sourced from octet m.
    const char* xs[8];
    #pragma unroll
    for (int q = 0; q < 8; ++q) {
        int pix = w * 64 + q * 8 + (lane >> 3);
        int g   = tile * TILE + pix;
        if (g >= GPIX) g = GPIX - 1;      // clamp; garbage cols discarded
        int b2 = g / NPIX;
        int rr = g - b2 * NPIX;
        int oy = rr / WOc;
        int ox = rr - oy * WOc;
        int m  = (lane & 7) ^ (pix & 7);  // source ci-octet for this slot
        xs[q] = (const char*)xt
            + ((((size_t)(b2 * Sn + s) << 10) + oy * 32 + ox) << 7) + (m << 4);
    }

    f32x16 acc[2][4];
    #pragma unroll
    for (int i = 0; i < 2; ++i)
        #pragma unroll
        for (int j = 0; j < 4; ++j)
            #pragma unroll
            for (int k = 0; k < 16; ++k)
                acc[i][j][k] = 0.f;

    #define STAGE(stepc, b)                                                  \
    {                                                                        \
        const char* ws_ = wsrcL + ((stepc) << 14);                           \
        char* wl_ = (char*)(&Wbuf[(b)][0]) + (w << 13);                      \
        _Pragma("unroll")                                                    \
        for (int q = 0; q < 8; ++q)                                          \
            gl16(ws_ + (q << 10), wl_ + (q << 10));                          \
        const int roff_ = (((stepc) / 3) * 32 + ((stepc) % 3)) * 128;        \
        char* xl_ = (char*)(&Xbuf[(b)][0]) + (w << 13);                      \
        _Pragma("unroll")                                                    \
        for (int q = 0; q < 8; ++q)                                          \
            gl16(xs[q] + roff_, xl_ + (q << 10));                            \
    }

    #define COMPUTE(b)                                                       \
    {                                                                        \
        const bf16* Wl_ = &Wbuf[(b)][0];                                     \
        const bf16* Xl_ = &Xbuf[(b)][0];                                     \
        _Pragma("unroll")                                                    \
        for (int kc = 0; kc < 4; ++kc) {                                     \
            const int oct_ = ((kc << 1) + (lane >> 5)) ^ (lane & 7);         \
            bf16x8 a0 = *reinterpret_cast<const bf16x8*>(                    \
                Wl_ + ((w * 64 + (lane & 31)) << 6) + (oct_ << 3));          \
            bf16x8 a1 = *reinterpret_cast<const bf16x8*>(                    \
                Wl_ + ((w * 64 + 32 + (lane & 31)) << 6) + (oct_ << 3));     \
            bf16x8 b0 = *reinterpret_cast<const bf16x8*>(                    \
                Xl_ + (((lane & 31)) << 6) + (oct_ << 3));                   \
            bf16x8 b1 = *reinterpret_cast<const bf16x8*>(                    \
                Xl_ + ((32 + (lane & 31)) << 6) + (oct_ << 3));              \
            bf16x8 b2 = *reinterpret_cast<const bf16x8*>(                    \
                Xl_ + ((64 + (lane & 31)) << 6) + (oct_ << 3));              \
            bf16x8 b3 = *reinterpret_cast<const bf16x8*>(                    \
                Xl_ + ((96 + (lane & 31)) << 6) + (oct_ << 3));              \
            acc[0][0] = __builtin_amdgcn_mfma_f32_32x32x16_bf16(a0, b0, acc[0][0], 0, 0, 0); \
            acc[0][1] = __builtin_amdgcn_mfma_f32_32x32x16_bf16(a0, b1, acc[0][1], 0, 0, 0); \
            acc[0][2] = __builtin_amdgcn_mfma_f32_32x32x16_bf16(a0, b2, acc[0][2], 0, 0, 0); \
            acc[0][3] = __builtin_amdgcn_mfma_f32_32x32x16_bf16(a0, b3, acc[0][3], 0, 0, 0); \
            acc[1][0] = __builtin_amdgcn_mfma_f32_32x32x16_bf16(a1, b0, acc[1][0], 0, 0, 0); \
            acc[1][1] = __builtin_amdgcn_mfma_f32_32x32x16_bf16(a1, b1, acc[1][1], 0, 0, 0); \
            acc[1][2] = __builtin_amdgcn_mfma_f32_32x32x16_bf16(a1, b2, acc[1][2], 0, 0, 0); \
            acc[1][3] = __builtin_amdgcn_mfma_f32_32x32x16_bf16(a1, b3, acc[1][3], 0, 0, 0); \
        }                                                                    \
    }

    // prologue: two stages in flight
    STAGE(0, 0);
    STAGE(1, 1);

    #define ITER(tt, b)                                                      \
        asm volatile("s_waitcnt vmcnt(16)" ::: "memory");                    \
        __builtin_amdgcn_s_barrier();                                        \
        __builtin_amdgcn_sched_barrier(0);                                   \
        COMPUTE(b);                                                          \
        __builtin_amdgcn_sched_barrier(0);                                   \
        __builtin_amdgcn_s_barrier();                                        \
        STAGE((tt) + 2, b);

    ITER(0, 0)
    ITER(1, 1)
    ITER(2, 0)
    ITER(3, 1)
    ITER(4, 0)
    ITER(5, 1)
    ITER(6, 0)
    // step 7 (buf 1): no further stage
    asm volatile("s_waitcnt vmcnt(16)" ::: "memory");
    __builtin_amdgcn_s_barrier();
    __builtin_amdgcn_sched_barrier(0);
    COMPUTE(1);
    // step 8 (buf 0): final, drain
    asm volatile("s_waitcnt vmcnt(0)" ::: "memory");
    __builtin_amdgcn_s_barrier();
    __builtin_amdgcn_sched_barrier(0);
    COMPUTE(0);

    #undef ITER
    #undef COMPUTE
    #undef STAGE

    // ---- epilogue: 32x32 C/D: col(pix)=lane&31, row(co)=(reg&3)+8*(reg>>2)+4*(lane>>5)
    const int colp = lane & 31;
    const int hi   = lane >> 5;
    #pragma unroll
    for (int i = 0; i < 2; ++i) {
        float bs[16];
        #pragma unroll
        for (int reg = 0; reg < 16; ++reg) {
            int co = w * 64 + i * 32 + (reg & 3) + 8 * (reg >> 2) + 4 * hi;
            bs[reg] = bq[s * COUTc + co];
        }
        #pragma unroll
        for (int j = 0; j < 4; ++j) {
            int gg = tile * TILE + j * 32 + colp;
            if (gg >= GPIX) continue;
            int b2 = gg / NPIX;
            int r2 = gg - b2 * NPIX;
            float* ob = out + (size_t)(b2 * Sn + s) * (COUTc * NPIX) + r2;
            #pragma unroll
            for (int reg = 0; reg < 16; ++reg) {
                int co = w * 64 + i * 32 + (reg & 3) + 8 * (reg >> 2) + 4 * hi;
                ob[co * NPIX] = acc[i][j][reg] + bs[reg];
            }
        }
    }

    // ---- KL finalize (block 0, wave 0): sum the 33 partial slots
    if (bid == 0 && w == 0) {
        float ls = 0.f, sq = 0.f;
        for (int i = lane; i < 33; i += 64) {
            ls += slots[2 * i];
            sq += slots[2 * i + 1];
        }
        #pragma unroll
        for (int off = 32; off > 0; off >>= 1) {
            ls += __shfl_down(ls, off);
            sq += __shfl_down(sq, off);
        }
        if (lane == 0)
            *klout = -ls + 0.91893853320467274f * (float)Pc + 0.5f * sq;
    }
}

// ---------------------------------------------------------------------------
extern "C" void kernel_launch(void* const* d_in, const int* in_sizes, int n_in,
                              void* d_out, int out_size, void* d_ws, size_t ws_size,
                              hipStream_t stream) {
    const float* x     = (const float*)d_in[0];
    const float* e     = (const float*)d_in[1];
    const float* mu_w  = (const float*)d_in[2];
    const float* rho_w = (const float*)d_in[3];
    const float* mu_b  = (const float*)d_in[4];
    const float* rho_b = (const float*)d_in[5];
    float* out = (float*)d_out;

    // workspace layout
    bf16*  wimg  = (bf16*)d_ws;                         // 1,179,648 B
    float* bq    = (float*)((char*)d_ws + 1179648);     // 4,096 B
    float* slots = (float*)((char*)d_ws + 1183744);     // 264 B (pad to 4K)
    bf16*  xt    = (bf16*)((char*)d_ws + 1187840);      // 8,388,608 B

    prep_all<<<dim3(545), dim3(256), 0, stream>>>(
        x, e, mu_w, rho_w, mu_b, rho_b, xt, wimg, bq, slots);

    conv_mfma<<<dim3(NT2 * Sn), dim3(128), 0, stream>>>(
        xt, wimg, bq, slots, out, out + (out_size - 1));
}